// Round 6
// baseline (217.143 us; speedup 1.0000x reference)
//
#include <hip/hip_runtime.h>

// CRF NLL, round 15: R12c (verified passing, absmax 0.0) with ONE change:
// the per-tt kc0/kc1 MFMA pair is de-chained (two Z-accumulated MFMAs + one
// f32 vector add) instead of C-chained.  Removes one full MFMA-result
// latency from the serial recursion and lets all 8 MFMAs issue
// back-to-back; the readfirstlane/SALU rescale overlaps the MFMA drain.
// All numerics (fp16 state, per-step exact pow2 rescale from full d0[0],
// fe ring, pkrtz pack, shuffle assembly) are identical to R12c.
//
// bf16 rounds R13/R14 NaN'd for reasons not derivable from the math;
// reverted to the verified fp16 pipeline. (R13/R14 delta machinery:
// cvt_pk_bf16 asm / f32 fe ring / uv4 element stores — one of these is
// bad; isolate later if more speed is needed.)
#define BB 512
#define SS 512
#define TT 64
#define START_TAG 62
#define STOP_TAG 63

#define LOG2E 1.4426950408889634f
#define LN2   0.6931471805599453f

typedef _Float16 h2 __attribute__((ext_vector_type(2)));
typedef _Float16 h8 __attribute__((ext_vector_type(8)));
typedef float    f4 __attribute__((ext_vector_type(4)));

__device__ __forceinline__ h2 pkrtz(float a, float b) {
    return __builtin_bit_cast(h2, __builtin_amdgcn_cvt_pkrtz(a, b));
}

__global__ void __launch_bounds__(128)
__attribute__((amdgpu_waves_per_eu(1, 1))) crf_main(
    const float* __restrict__ feats, const int* __restrict__ mask,
    const int* __restrict__ tags, const float* __restrict__ trans,
    float* __restrict__ out)
{
    const int b    = blockIdx.x;
    const int tid  = threadIdx.x;
    const int lane = tid & 63;

    const float* frow = feats + (size_t)b * SS * TT;
    const int*   mrow = mask + b * SS;

    // fe ring: 8 rows of 64 fp16 (1 KiB); row s holds exp(feats[b][s][t])
    __shared__ __align__(16) _Float16 febuf[8][TT];

    if (tid < 64) {
        // ---------------- forward (log partition), wave 0 ----------------
        const int g  = lane >> 4;   // k-group / slot-group 0..3
        const int cg = lane & 15;   // replicated column index

        int cnt = 0;
        #pragma unroll
        for (int s = lane; s < SS; s += 64) cnt += (mrow[s] != 0);
        #pragma unroll
        for (int off = 32; off; off >>= 1) cnt += __shfl_xor(cnt, off);
        const int len = cnt;                      // in [SS/2, SS]

        // A fragments: A[tt][kc], lane holds row i = cg, k = 8g..8g+7 of the
        // kc-th K=32 chunk.  Value = exp(trans[tag_in][tag_out]) with
        //   tag_in  = 16g + 8kc + j
        //   tag_out = 16*(cg>>2) + 4tt + (cg&3)
        const int to_base   = 16 * (cg >> 2) + (cg & 3);
        const int from_base = 16 * g;
        h8 A[4][2];
        #pragma unroll
        for (int tt = 0; tt < 4; ++tt)
            #pragma unroll
            for (int kc = 0; kc < 2; ++kc)
                #pragma unroll
                for (int j = 0; j < 8; ++j)
                    A[tt][kc][j] = (_Float16)__builtin_amdgcn_exp2f(
                        trans[(from_base + 8 * kc + j) * TT
                              + (to_base + 4 * tt)] * LOG2E);

        // init: P0[t] = f[0,t] + trans[START,t];  E = e^(P0-offs), slot order:
        // lane holds slots 16g..16g+15 (B0 = slots 0..7, B1 = 8..15 of group)
        const float offs = frow[0] + trans[START_TAG * TT + 0];  // wave-uniform
        h8 B0, B1;
        #pragma unroll
        for (int sl = 0; sl < 8; ++sl) {
            const int t0 = 16 * g + sl, t1 = t0 + 8;
            B0[sl] = (_Float16)__builtin_amdgcn_exp2f(
                (frow[t0] + trans[START_TAG * TT + t0] - offs) * LOG2E);
            B1[sl] = (_Float16)__builtin_amdgcn_exp2f(
                (frow[t1] + trans[START_TAG * TT + t1] - offs) * LOG2E);
        }
        int ksum = 0;
        const f4 Z = {0.f, 0.f, 0.f, 0.f};

        // 8-deep raw-feat ring (rows s..s+7 for s=1)
        float fr[8];
        #pragma unroll
        for (int j = 0; j < 8; ++j) {
            int r = 1 + j; if (r > SS - 1) r = SS - 1;
            fr[j] = frow[(size_t)r * TT + lane];
        }
        // prologue: fe rows for steps 1..4
        #pragma unroll
        for (int j = 0; j < 4; ++j)
            febuf[(1 + j) & 7][lane] =
                (_Float16)__builtin_amdgcn_exp2f(fr[j] * LOG2E);

        auto step = [&](int row) {
            // fe for this step: uniform within each 16-lane group (broadcast)
            const _Float16* fb = &febuf[row & 7][16 * g];
            const h8 fe0 = *(const h8*)(fb);
            const h8 fe1 = *(const h8*)(fb + 8);
            // D = M^T * E: 8 INDEPENDENT MFMAs (no C-chain), then f32 adds
            const f4 dl0 = __builtin_amdgcn_mfma_f32_16x16x32_f16(A[0][0], B0, Z, 0, 0, 0);
            const f4 dh0 = __builtin_amdgcn_mfma_f32_16x16x32_f16(A[0][1], B1, Z, 0, 0, 0);
            const f4 dl1 = __builtin_amdgcn_mfma_f32_16x16x32_f16(A[1][0], B0, Z, 0, 0, 0);
            const f4 dh1 = __builtin_amdgcn_mfma_f32_16x16x32_f16(A[1][1], B1, Z, 0, 0, 0);
            const f4 dl2 = __builtin_amdgcn_mfma_f32_16x16x32_f16(A[2][0], B0, Z, 0, 0, 0);
            const f4 dh2 = __builtin_amdgcn_mfma_f32_16x16x32_f16(A[2][1], B1, Z, 0, 0, 0);
            const f4 dl3 = __builtin_amdgcn_mfma_f32_16x16x32_f16(A[3][0], B0, Z, 0, 0, 0);
            const f4 dh3 = __builtin_amdgcn_mfma_f32_16x16x32_f16(A[3][1], B1, Z, 0, 0, 0);
            const f4 d0 = dl0 + dh0;          // full D for tags 16g+0..3
            // exact pow2 rescale, representative = tag 0 (d0 reg0, lane 0);
            // SALU exponent math overlaps the tt=1..3 MFMA drain
            const int eb = (__builtin_amdgcn_readfirstlane(
                                __float_as_int(d0[0])) >> 23) & 0xff;
            ksum += eb - 127;
            const float sc = __int_as_float((254 - eb) << 23);
            const f4 d1 = dl1 + dh1;
            const f4 d2 = dl2 + dh2;
            const f4 d3 = dl3 + dh3;
            // E' = (D*sc) * fe, packed fp16; slot = 4*tt + reg
            const h2 p0 = pkrtz(d0[0] * sc, d0[1] * sc);
            const h2 p1 = pkrtz(d0[2] * sc, d0[3] * sc);
            const h2 p2 = pkrtz(d1[0] * sc, d1[1] * sc);
            const h2 p3 = pkrtz(d1[2] * sc, d1[3] * sc);
            const h2 p4 = pkrtz(d2[0] * sc, d2[1] * sc);
            const h2 p5 = pkrtz(d2[2] * sc, d2[3] * sc);
            const h2 p6 = pkrtz(d3[0] * sc, d3[1] * sc);
            const h2 p7 = pkrtz(d3[2] * sc, d3[3] * sc);
            const h2 q0 = p0 * __builtin_shufflevector(fe0, fe0, 0, 1);
            const h2 q1 = p1 * __builtin_shufflevector(fe0, fe0, 2, 3);
            const h2 q2 = p2 * __builtin_shufflevector(fe0, fe0, 4, 5);
            const h2 q3 = p3 * __builtin_shufflevector(fe0, fe0, 6, 7);
            const h2 q4 = p4 * __builtin_shufflevector(fe1, fe1, 0, 1);
            const h2 q5 = p5 * __builtin_shufflevector(fe1, fe1, 2, 3);
            const h2 q6 = p6 * __builtin_shufflevector(fe1, fe1, 4, 5);
            const h2 q7 = p7 * __builtin_shufflevector(fe1, fe1, 6, 7);
            B0 = __builtin_shufflevector(
                     __builtin_shufflevector(q0, q1, 0, 1, 2, 3),
                     __builtin_shufflevector(q2, q3, 0, 1, 2, 3),
                     0, 1, 2, 3, 4, 5, 6, 7);
            B1 = __builtin_shufflevector(
                     __builtin_shufflevector(q4, q5, 0, 1, 2, 3),
                     __builtin_shufflevector(q6, q7, 0, 1, 2, 3),
                     0, 1, 2, 3, 4, 5, 6, 7);
        };

        int s = 1;
        for (; s + 3 < len; s += 4) {
            // prefetch raw feats rows s+8..s+11 (consumed 8 steps later)
            float n0, n1, n2, n3;
            {
                int r0 = s + 8, r1 = s + 9, r2 = s + 10, r3 = s + 11;
                if (r0 > SS - 1) r0 = SS - 1;
                if (r1 > SS - 1) r1 = SS - 1;
                if (r2 > SS - 1) r2 = SS - 1;
                if (r3 > SS - 1) r3 = SS - 1;
                n0 = frow[(size_t)r0 * TT + lane];
                n1 = frow[(size_t)r1 * TT + lane];
                n2 = frow[(size_t)r2 * TT + lane];
                n3 = frow[(size_t)r3 * TT + lane];
            }
            // fe rows s+4..s+7 (read next iteration; disjoint mod 8 from s..s+3)
            febuf[(s + 4) & 7][lane] =
                (_Float16)__builtin_amdgcn_exp2f(fr[4] * LOG2E);
            febuf[(s + 5) & 7][lane] =
                (_Float16)__builtin_amdgcn_exp2f(fr[5] * LOG2E);
            febuf[(s + 6) & 7][lane] =
                (_Float16)__builtin_amdgcn_exp2f(fr[6] * LOG2E);
            febuf[(s + 7) & 7][lane] =
                (_Float16)__builtin_amdgcn_exp2f(fr[7] * LOG2E);

            step(s); step(s + 1); step(s + 2); step(s + 3);

            #pragma unroll
            for (int j = 0; j < 4; ++j) fr[j] = fr[j + 4];
            fr[4] = n0; fr[5] = n1; fr[6] = n2; fr[7] = n3;
        }

        // tail: fe rows s..s+2 were written by the last full iteration
        const int rem = len - s;   // 0..3
        if (rem > 0) step(s);
        if (rem > 1) step(s + 1);
        if (rem > 2) step(s + 2);

        // final transition to STOP: sum_from E[from] * exp(trans[from,STOP])
        float e = 0.f;
        #pragma unroll
        for (int sl = 0; sl < 8; ++sl) {
            const int t0 = 16 * g + sl, t1 = t0 + 8;
            e += (float)B0[sl] * __builtin_amdgcn_exp2f(
                     trans[t0 * TT + STOP_TAG] * LOG2E);
            e += (float)B1[sl] * __builtin_amdgcn_exp2f(
                     trans[t1 * TT + STOP_TAG] * LOG2E);
        }
        // values replicated within a group; reduce across the 4 groups
        e += __shfl_xor(e, 16);
        e += __shfl_xor(e, 32);

        if (lane == 0)
            atomicAdd(out, offs + (float)ksum * LN2
                           + LN2 * __builtin_amdgcn_logf(e));
    } else {
        // ---------------- gold score, wave 1 of the block --------------------
        const int* trow = tags + b * SS;
        int   cnt = 0;
        float acc = 0.f;
        for (int s = lane; s < SS; s += 64) {
            if (mrow[s] != 0) {
                ++cnt;
                const int tag  = trow[s];
                const int prev = (s == 0) ? START_TAG : trow[s - 1];
                acc += frow[(size_t)s * TT + tag] + trans[prev * TT + tag];
            }
        }
        #pragma unroll
        for (int off = 32; off; off >>= 1) {
            acc += __shfl_xor(acc, off);
            cnt += __shfl_xor(cnt, off);
        }
        if (lane == 0) {
            const int end_id = trow[cnt - 1];
            atomicAdd(out, -(acc + trans[end_id * TT + STOP_TAG]));
        }
    }
}

extern "C" void kernel_launch(void* const* d_in, const int* in_sizes, int n_in,
                              void* d_out, int out_size, void* d_ws, size_t ws_size,
                              hipStream_t stream) {
    const float* feats = (const float*)d_in[0];   // (B,S,T) f32
    const int*   mask  = (const int*)d_in[1];     // (B,S)   int (0/1)
    const int*   tags  = (const int*)d_in[2];     // (B,S)   int
    const float* trans = (const float*)d_in[3];   // (T,T)   f32
    float* out = (float*)d_out;

    (void)hipMemsetAsync(out, 0, sizeof(float), stream);
    crf_main<<<BB, 128, 0, stream>>>(feats, mask, tags, trans, out);
}

// Round 7
// 185.962 us; speedup vs baseline: 1.1677x; 1.1677x over previous
//
#include <hip/hip_runtime.h>

// CRF NLL, round 16: bidirectional split of the serial chain.
// forward:  G_s = (M^T diag(fe_{s-1})) G_{s-1}   (fe folded into A, off-chain)
// backward: w_{s-1} = (M diag(fe_s)) w_s         (adjoint chain, trans swapped)
// meet at h=len/2:  Z = sum_t (fe_h[t]*G_h[t]) * w_h[t]
// Each chain ~len/2 steps instead of len-1 -> 2x on the latency-bound
// critical path (R12c measured 520 cy/step, machine otherwise idle).
// Per-step: A' = A (*) fe8 (32 pk_mul, off-chain; fe prefetched in regs one
// iteration ahead), 8 MFMAs C-chained per kc pair (R15: Z+add was slower),
// exact per-step pow2 rescale (R12c semantics, verified absmax 0.0).
// Block = 192: wave0 fwd chain, wave1 bwd chain, wave2 gold score.
#define BB 512
#define SS 512
#define TT 64
#define START_TAG 62
#define STOP_TAG 63

#define LOG2E 1.4426950408889634f
#define LN2   0.6931471805599453f

typedef _Float16 h2 __attribute__((ext_vector_type(2)));
typedef _Float16 h8 __attribute__((ext_vector_type(8)));
typedef float    f4 __attribute__((ext_vector_type(4)));

__device__ __forceinline__ h2 pkrtz(float a, float b) {
    return __builtin_bit_cast(h2, __builtin_amdgcn_cvt_pkrtz(a, b));
}
__device__ __forceinline__ f4 MF(h8 a, h8 b, f4 c) {
    return __builtin_amdgcn_mfma_f32_16x16x32_f16(a, b, c, 0, 0, 0);
}

__global__ void __launch_bounds__(192) crf_main(
    const float* __restrict__ feats, const int* __restrict__ mask,
    const int* __restrict__ tags, const float* __restrict__ trans,
    float* __restrict__ out)
{
    const int b    = blockIdx.x;
    const int tid  = threadIdx.x;
    const int wv   = tid >> 6;
    const int lane = tid & 63;

    const float* frow = feats + (size_t)b * SS * TT;
    const int*   mrow = mask + b * SS;

    // per-chain-wave fe ring (raw exp(feat), fp16), 8 rows each
    __shared__ __align__(16) _Float16 febuf[2][8][TT];
    __shared__ __align__(16) float xbuf[TT];   // fwd G_h (f32)
    __shared__ __align__(16) float ybuf[TT];   // bwd w_h (f32)
    __shared__ int ks_sh[2];

    // sequence length (all waves compute it; cheap)
    int cnt = 0;
    #pragma unroll
    for (int s = lane; s < SS; s += 64) cnt += (mrow[s] != 0);
    #pragma unroll
    for (int off = 32; off; off >>= 1) cnt += __shfl_xor(cnt, off);
    const int len = cnt;            // in [SS/2, SS]
    const int h   = len >> 1;       // meet point

    float offs = 0.f;
    int   ksum = 0;

    if (wv < 2) {
        // ------------- chain wave: wv0 = forward, wv1 = backward -------------
        const bool isF = (wv == 0);
        const int g  = lane >> 4;
        const int cg = lane & 15;
        const int to_base   = 16 * (cg >> 2) + (cg & 3);
        const int nstep = isF ? h : (len - 1 - h);          // both >= 127
        const int r0    = isF ? 0 : (len - 1);
        const int dir   = isF ? 1 : -1;
        _Float16 (*febw)[TT] = febuf[wv];

        // A fragments: out-tag relabeled (D->B identity), k-tag raw.
        // fwd value = exp(trans[kt][ot]); bwd (adjoint) = exp(trans[ot][kt]).
        h8 A[4][2];
        #pragma unroll
        for (int tt = 0; tt < 4; ++tt)
            #pragma unroll
            for (int kc = 0; kc < 2; ++kc)
                #pragma unroll
                for (int j = 0; j < 8; ++j) {
                    const int kt = 16 * g + 8 * kc + j;
                    const int ot = to_base + 4 * tt;
                    const int ix = isF ? (kt * TT + ot) : (ot * TT + kt);
                    A[tt][kc][j] =
                        (_Float16)__builtin_amdgcn_exp2f(trans[ix] * LOG2E);
                }

        // B init (slots = raw tags 16g+sl).
        // fwd: Binit[t] = exp(trans[START][t] - offs)   (fe_0 folded in step 0)
        // bwd: w_init[t] = exp(trans[t][STOP])
        h8 B0, B1;
        if (isF) {
            offs = frow[0] + trans[START_TAG * TT + 0];   // wave-uniform
            #pragma unroll
            for (int sl = 0; sl < 8; ++sl) {
                const int t0 = 16 * g + sl, t1 = t0 + 8;
                B0[sl] = (_Float16)__builtin_amdgcn_exp2f(
                    (trans[START_TAG * TT + t0] - offs) * LOG2E);
                B1[sl] = (_Float16)__builtin_amdgcn_exp2f(
                    (trans[START_TAG * TT + t1] - offs) * LOG2E);
            }
        } else {
            #pragma unroll
            for (int sl = 0; sl < 8; ++sl) {
                const int t0 = 16 * g + sl, t1 = t0 + 8;
                B0[sl] = (_Float16)__builtin_amdgcn_exp2f(
                    trans[t0 * TT + STOP_TAG] * LOG2E);
                B1[sl] = (_Float16)__builtin_amdgcn_exp2f(
                    trans[t1 * TT + STOP_TAG] * LOG2E);
            }
        }

        auto rowOf = [&](int idx) {
            int r = r0 + dir * idx;
            return r < 0 ? 0 : (r > SS - 1 ? SS - 1 : r);
        };

        // raw-feat ring (rows for steps i..i+7)
        float fr[8];
        #pragma unroll
        for (int j = 0; j < 8; ++j)
            fr[j] = frow[(size_t)rowOf(j) * TT + lane];
        // prologue: fe rows for steps 0..3
        #pragma unroll
        for (int j = 0; j < 4; ++j)
            febw[rowOf(j) & 7][lane] =
                (_Float16)__builtin_amdgcn_exp2f(fr[j] * LOG2E);
        // preload fe regs for steps 0..3 (group-broadcast b128 reads)
        h8 cL0, cL1, cL2, cL3, cH0, cH1, cH2, cH3;
        {
            const _Float16* p0 = &febw[rowOf(0) & 7][16 * g];
            const _Float16* p1 = &febw[rowOf(1) & 7][16 * g];
            const _Float16* p2 = &febw[rowOf(2) & 7][16 * g];
            const _Float16* p3 = &febw[rowOf(3) & 7][16 * g];
            cL0 = *(const h8*)p0; cH0 = *(const h8*)(p0 + 8);
            cL1 = *(const h8*)p1; cH1 = *(const h8*)(p1 + 8);
            cL2 = *(const h8*)p2; cH2 = *(const h8*)(p2 + 8);
            cL3 = *(const h8*)p3; cH3 = *(const h8*)(p3 + 8);
        }

        const f4 Z = {0.f, 0.f, 0.f, 0.f};
        auto STEP = [&](h8 feL, h8 feH) {
            // A' = A (*) fe8 (k-side fold; 32 v_pk_mul_f16, off the chain)
            const h8 a00 = A[0][0] * feL, a01 = A[0][1] * feH;
            const h8 a10 = A[1][0] * feL, a11 = A[1][1] * feH;
            const h8 a20 = A[2][0] * feL, a21 = A[2][1] * feH;
            const h8 a30 = A[3][0] * feL, a31 = A[3][1] * feH;
            const f4 d0 = MF(a01, B1, MF(a00, B0, Z));
            const f4 d1 = MF(a11, B1, MF(a10, B0, Z));
            const f4 d2 = MF(a21, B1, MF(a20, B0, Z));
            const f4 d3 = MF(a31, B1, MF(a30, B0, Z));
            // exact pow2 rescale, representative = tag 0 (lane0 d0[0])
            const int eb = (__builtin_amdgcn_readfirstlane(
                                __float_as_int(d0[0])) >> 23) & 0xff;
            ksum += eb - 127;
            const float sc = __int_as_float((254 - eb) << 23);
            const h2 p0 = pkrtz(d0[0] * sc, d0[1] * sc);
            const h2 p1 = pkrtz(d0[2] * sc, d0[3] * sc);
            const h2 p2 = pkrtz(d1[0] * sc, d1[1] * sc);
            const h2 p3 = pkrtz(d1[2] * sc, d1[3] * sc);
            const h2 p4 = pkrtz(d2[0] * sc, d2[1] * sc);
            const h2 p5 = pkrtz(d2[2] * sc, d2[3] * sc);
            const h2 p6 = pkrtz(d3[0] * sc, d3[1] * sc);
            const h2 p7 = pkrtz(d3[2] * sc, d3[3] * sc);
            B0 = __builtin_shufflevector(
                     __builtin_shufflevector(p0, p1, 0, 1, 2, 3),
                     __builtin_shufflevector(p2, p3, 0, 1, 2, 3),
                     0, 1, 2, 3, 4, 5, 6, 7);
            B1 = __builtin_shufflevector(
                     __builtin_shufflevector(p4, p5, 0, 1, 2, 3),
                     __builtin_shufflevector(p6, p7, 0, 1, 2, 3),
                     0, 1, 2, 3, 4, 5, 6, 7);
        };

        int i = 0;
        for (; i + 3 < nstep; i += 4) {
            // prefetch raw feats rows for steps i+8..i+11
            const float n0 = frow[(size_t)rowOf(i + 8)  * TT + lane];
            const float n1 = frow[(size_t)rowOf(i + 9)  * TT + lane];
            const float n2 = frow[(size_t)rowOf(i + 10) * TT + lane];
            const float n3 = frow[(size_t)rowOf(i + 11) * TT + lane];
            // write fe rows for steps i+4..i+7 (disjoint mod 8 from i..i+3)
            febw[rowOf(i + 4) & 7][lane] =
                (_Float16)__builtin_amdgcn_exp2f(fr[4] * LOG2E);
            febw[rowOf(i + 5) & 7][lane] =
                (_Float16)__builtin_amdgcn_exp2f(fr[5] * LOG2E);
            febw[rowOf(i + 6) & 7][lane] =
                (_Float16)__builtin_amdgcn_exp2f(fr[6] * LOG2E);
            febw[rowOf(i + 7) & 7][lane] =
                (_Float16)__builtin_amdgcn_exp2f(fr[7] * LOG2E);
            // read next iteration's fe regs (latency hidden under 4 steps)
            const _Float16* q0 = &febw[rowOf(i + 4) & 7][16 * g];
            const _Float16* q1 = &febw[rowOf(i + 5) & 7][16 * g];
            const _Float16* q2 = &febw[rowOf(i + 6) & 7][16 * g];
            const _Float16* q3 = &febw[rowOf(i + 7) & 7][16 * g];
            const h8 nL0 = *(const h8*)q0, nH0 = *(const h8*)(q0 + 8);
            const h8 nL1 = *(const h8*)q1, nH1 = *(const h8*)(q1 + 8);
            const h8 nL2 = *(const h8*)q2, nH2 = *(const h8*)(q2 + 8);
            const h8 nL3 = *(const h8*)q3, nH3 = *(const h8*)(q3 + 8);

            STEP(cL0, cH0); STEP(cL1, cH1); STEP(cL2, cH2); STEP(cL3, cH3);

            cL0 = nL0; cH0 = nH0; cL1 = nL1; cH1 = nH1;
            cL2 = nL2; cH2 = nH2; cL3 = nL3; cH3 = nH3;
            #pragma unroll
            for (int j = 0; j < 4; ++j) fr[j] = fr[j + 4];
            fr[4] = n0; fr[5] = n1; fr[6] = n2; fr[7] = n3;
        }

        // tail (fe regs for steps i..i+2 already in cL*/cH*)
        const int rem = nstep - i;   // 0..3
        if (rem > 0) STEP(cL0, cH0);
        if (rem > 1) STEP(cL1, cH1);
        if (rem > 2) STEP(cL2, cH2);

        // publish state (replicated across cg; cg==0 lanes write)
        float* obuf = isF ? xbuf : ybuf;
        if (cg == 0) {
            #pragma unroll
            for (int sl = 0; sl < 8; ++sl) {
                obuf[16 * g + sl]     = (float)B0[sl];
                obuf[16 * g + 8 + sl] = (float)B1[sl];
            }
        }
        if (lane == 0) ks_sh[wv] = ksum;
    } else {
        // ---------------- gold score, wave 2 --------------------------------
        const int* trow = tags + b * SS;
        int   gcnt = 0;
        float acc  = 0.f;
        for (int s = lane; s < SS; s += 64) {
            if (mrow[s] != 0) {
                ++gcnt;
                const int tag  = trow[s];
                const int prev = (s == 0) ? START_TAG : trow[s - 1];
                acc += frow[(size_t)s * TT + tag] + trans[prev * TT + tag];
            }
        }
        #pragma unroll
        for (int off = 32; off; off >>= 1) acc += __shfl_xor(acc, off);
        if (lane == 0) {
            const int end_id = trow[len - 1];
            atomicAdd(out, -(acc + trans[end_id * TT + STOP_TAG]));
        }
    }

    __syncthreads();

    if (wv == 0) {
        // Z = sum_t (fe_h[t] * G_h[t]) * w_h[t]
        float z = xbuf[lane] * ybuf[lane] *
                  __builtin_amdgcn_exp2f(frow[(size_t)h * TT + lane] * LOG2E);
        #pragma unroll
        for (int off = 32; off; off >>= 1) z += __shfl_xor(z, off);
        if (lane == 0)
            atomicAdd(out, offs + (float)(ksum + ks_sh[1]) * LN2
                           + LN2 * __builtin_amdgcn_logf(z));
    }
}

extern "C" void kernel_launch(void* const* d_in, const int* in_sizes, int n_in,
                              void* d_out, int out_size, void* d_ws, size_t ws_size,
                              hipStream_t stream) {
    const float* feats = (const float*)d_in[0];   // (B,S,T) f32
    const int*   mask  = (const int*)d_in[1];     // (B,S)   int (0/1)
    const int*   tags  = (const int*)d_in[2];     // (B,S)   int
    const float* trans = (const float*)d_in[3];   // (T,T)   f32
    float* out = (float*)d_out;

    (void)hipMemsetAsync(out, 0, sizeof(float), stream);
    crf_main<<<BB, 192, 0, stream>>>(feats, mask, tags, trans, out);
}

// Round 8
// 166.791 us; speedup vs baseline: 1.3019x; 1.1149x over previous
//
#include <hip/hip_runtime.h>

// CRF NLL, round 17: bidirectional split (R16 machinery, verified absmax 0.0)
// + the LEAN R12c step body (measured 520 cy/step vs R16's A-fold 1000).
//
// R16 lesson: waves issue in-order, so the 32 pk_mul A-fold between chain
// tail (pkrtz) and chain head (MFMA) doubled the step. R17 restores R12c's
// output-side fe fold (8 h2 muls after pkrtz).
//
// fwd:  E_s = fe_s (*) (M^T E_{s-1}),  s=1..h;  then V = M^T E_h (bare)
// bwd:  u_{len-1} = exp(f_{len-1}+trans[:,STOP]);
//       u_s = fe_s (*) (M u_{s+1}),    s=len-2..h+1
// Z = sum_t V[t]*u_{h+1}[t];  logZ = offs + (ksf+ksb)*ln2 + ln(Z)
// Per-step exact pow2 rescale (verified), tag relabeling (verified) makes
// MFMA D fragments land exactly in the next step's B operand.
#define BB 512
#define SS 512
#define TT 64
#define START_TAG 62
#define STOP_TAG 63

#define LOG2E 1.4426950408889634f
#define LN2   0.6931471805599453f

typedef _Float16 h2 __attribute__((ext_vector_type(2)));
typedef _Float16 h8 __attribute__((ext_vector_type(8)));
typedef float    f4 __attribute__((ext_vector_type(4)));

__device__ __forceinline__ h2 pkrtz(float a, float b) {
    return __builtin_bit_cast(h2, __builtin_amdgcn_cvt_pkrtz(a, b));
}
__device__ __forceinline__ f4 MF(h8 a, h8 b, f4 c) {
    return __builtin_amdgcn_mfma_f32_16x16x32_f16(a, b, c, 0, 0, 0);
}

__global__ void __launch_bounds__(192) crf_main(
    const float* __restrict__ feats, const int* __restrict__ mask,
    const int* __restrict__ tags, const float* __restrict__ trans,
    float* __restrict__ out)
{
    const int b    = blockIdx.x;
    const int tid  = threadIdx.x;
    const int wv   = tid >> 6;
    const int lane = tid & 63;

    const float* frow = feats + (size_t)b * SS * TT;
    const int*   mrow = mask + b * SS;

    __shared__ __align__(16) _Float16 febuf[2][8][TT];
    __shared__ __align__(16) float xbuf[TT];   // V = M^T E_h (f32)
    __shared__ __align__(16) float ybuf[TT];   // u_{h+1}     (f32)
    __shared__ int ks_sh;                      // bwd ksum

    int cnt = 0;
    #pragma unroll
    for (int s = lane; s < SS; s += 64) cnt += (mrow[s] != 0);
    #pragma unroll
    for (int off = 32; off; off >>= 1) cnt += __shfl_xor(cnt, off);
    const int len = cnt;            // in [SS/2, SS]
    const int h   = len >> 1;

    float offs = 0.f;
    int   ksum = 0;

    if (wv < 2) {
        // ------------- chain wave: wv0 = forward, wv1 = backward -------------
        const bool isF = (wv == 0);
        const int g  = lane >> 4;
        const int cg = lane & 15;
        const int to_base = 16 * (cg >> 2) + (cg & 3);
        const int nstep = isF ? h : (len - h - 2);
        const int base  = isF ? 1 : (len - 2);   // fe row of step i = base+dir*i
        const int dir   = isF ? 1 : -1;
        _Float16 (*febw)[TT] = febuf[wv];

        // A fragments: fwd = exp(trans[kt][ot]) (M^T), bwd = exp(trans[ot][kt]) (M)
        h8 A[4][2];
        #pragma unroll
        for (int tt = 0; tt < 4; ++tt)
            #pragma unroll
            for (int kc = 0; kc < 2; ++kc)
                #pragma unroll
                for (int j = 0; j < 8; ++j) {
                    const int kt = 16 * g + 8 * kc + j;
                    const int ot = to_base + 4 * tt;
                    const int ix = isF ? (kt * TT + ot) : (ot * TT + kt);
                    A[tt][kc][j] =
                        (_Float16)__builtin_amdgcn_exp2f(trans[ix] * LOG2E);
                }

        // B init (slots = raw tags 16g+sl)
        h8 B0, B1;
        if (isF) {
            offs = frow[0] + trans[START_TAG * TT + 0];   // wave-uniform
            #pragma unroll
            for (int sl = 0; sl < 8; ++sl) {
                const int t0 = 16 * g + sl, t1 = t0 + 8;
                B0[sl] = (_Float16)__builtin_amdgcn_exp2f(
                    (frow[t0] + trans[START_TAG * TT + t0] - offs) * LOG2E);
                B1[sl] = (_Float16)__builtin_amdgcn_exp2f(
                    (frow[t1] + trans[START_TAG * TT + t1] - offs) * LOG2E);
            }
        } else {
            const float* fl = frow + (size_t)(len - 1) * TT;
            #pragma unroll
            for (int sl = 0; sl < 8; ++sl) {
                const int t0 = 16 * g + sl, t1 = t0 + 8;
                B0[sl] = (_Float16)__builtin_amdgcn_exp2f(
                    (fl[t0] + trans[t0 * TT + STOP_TAG]) * LOG2E);
                B1[sl] = (_Float16)__builtin_amdgcn_exp2f(
                    (fl[t1] + trans[t1 * TT + STOP_TAG]) * LOG2E);
            }
        }

        auto rowOf = [&](int idx) {
            int r = base + dir * idx;
            return r < 0 ? 0 : (r > SS - 1 ? SS - 1 : r);
        };

        // raw-feat ring (rows for steps i..i+7)
        float fr[8];
        #pragma unroll
        for (int j = 0; j < 8; ++j)
            fr[j] = frow[(size_t)rowOf(j) * TT + lane];
        // prologue: fe rows for steps 0..3
        #pragma unroll
        for (int j = 0; j < 4; ++j)
            febw[rowOf(j) & 7][lane] =
                (_Float16)__builtin_amdgcn_exp2f(fr[j] * LOG2E);
        // fe regs for steps 0..3 (group-broadcast b128 reads)
        h8 cL0, cL1, cL2, cL3, cH0, cH1, cH2, cH3;
        {
            const _Float16* p0 = &febw[rowOf(0) & 7][16 * g];
            const _Float16* p1 = &febw[rowOf(1) & 7][16 * g];
            const _Float16* p2 = &febw[rowOf(2) & 7][16 * g];
            const _Float16* p3 = &febw[rowOf(3) & 7][16 * g];
            cL0 = *(const h8*)p0; cH0 = *(const h8*)(p0 + 8);
            cL1 = *(const h8*)p1; cH1 = *(const h8*)(p1 + 8);
            cL2 = *(const h8*)p2; cH2 = *(const h8*)(p2 + 8);
            cL3 = *(const h8*)p3; cH3 = *(const h8*)(p3 + 8);
        }

        const f4 Z = {0.f, 0.f, 0.f, 0.f};
        // LEAN step (R12c body): MFMA on stored A, fe folded output-side
        auto STEP = [&](h8 feL, h8 feH) {
            f4 d0 = MF(A[0][0], B0, Z);
            f4 d1 = MF(A[1][0], B0, Z);
            f4 d2 = MF(A[2][0], B0, Z);
            f4 d3 = MF(A[3][0], B0, Z);
            d0 = MF(A[0][1], B1, d0);
            d1 = MF(A[1][1], B1, d1);
            d2 = MF(A[2][1], B1, d2);
            d3 = MF(A[3][1], B1, d3);
            const int eb = (__builtin_amdgcn_readfirstlane(
                                __float_as_int(d0[0])) >> 23) & 0xff;
            ksum += eb - 127;
            const float sc = __int_as_float((254 - eb) << 23);
            const h2 p0 = pkrtz(d0[0] * sc, d0[1] * sc);
            const h2 p1 = pkrtz(d0[2] * sc, d0[3] * sc);
            const h2 p2 = pkrtz(d1[0] * sc, d1[1] * sc);
            const h2 p3 = pkrtz(d1[2] * sc, d1[3] * sc);
            const h2 p4 = pkrtz(d2[0] * sc, d2[1] * sc);
            const h2 p5 = pkrtz(d2[2] * sc, d2[3] * sc);
            const h2 p6 = pkrtz(d3[0] * sc, d3[1] * sc);
            const h2 p7 = pkrtz(d3[2] * sc, d3[3] * sc);
            const h2 q0 = p0 * __builtin_shufflevector(feL, feL, 0, 1);
            const h2 q1 = p1 * __builtin_shufflevector(feL, feL, 2, 3);
            const h2 q2 = p2 * __builtin_shufflevector(feL, feL, 4, 5);
            const h2 q3 = p3 * __builtin_shufflevector(feL, feL, 6, 7);
            const h2 q4 = p4 * __builtin_shufflevector(feH, feH, 0, 1);
            const h2 q5 = p5 * __builtin_shufflevector(feH, feH, 2, 3);
            const h2 q6 = p6 * __builtin_shufflevector(feH, feH, 4, 5);
            const h2 q7 = p7 * __builtin_shufflevector(feH, feH, 6, 7);
            B0 = __builtin_shufflevector(
                     __builtin_shufflevector(q0, q1, 0, 1, 2, 3),
                     __builtin_shufflevector(q2, q3, 0, 1, 2, 3),
                     0, 1, 2, 3, 4, 5, 6, 7);
            B1 = __builtin_shufflevector(
                     __builtin_shufflevector(q4, q5, 0, 1, 2, 3),
                     __builtin_shufflevector(q6, q7, 0, 1, 2, 3),
                     0, 1, 2, 3, 4, 5, 6, 7);
        };

        int i = 0;
        for (; i + 3 < nstep; i += 4) {
            const float n0 = frow[(size_t)rowOf(i + 8)  * TT + lane];
            const float n1 = frow[(size_t)rowOf(i + 9)  * TT + lane];
            const float n2 = frow[(size_t)rowOf(i + 10) * TT + lane];
            const float n3 = frow[(size_t)rowOf(i + 11) * TT + lane];
            febw[rowOf(i + 4) & 7][lane] =
                (_Float16)__builtin_amdgcn_exp2f(fr[4] * LOG2E);
            febw[rowOf(i + 5) & 7][lane] =
                (_Float16)__builtin_amdgcn_exp2f(fr[5] * LOG2E);
            febw[rowOf(i + 6) & 7][lane] =
                (_Float16)__builtin_amdgcn_exp2f(fr[6] * LOG2E);
            febw[rowOf(i + 7) & 7][lane] =
                (_Float16)__builtin_amdgcn_exp2f(fr[7] * LOG2E);
            const _Float16* q0p = &febw[rowOf(i + 4) & 7][16 * g];
            const _Float16* q1p = &febw[rowOf(i + 5) & 7][16 * g];
            const _Float16* q2p = &febw[rowOf(i + 6) & 7][16 * g];
            const _Float16* q3p = &febw[rowOf(i + 7) & 7][16 * g];
            const h8 nL0 = *(const h8*)q0p, nH0 = *(const h8*)(q0p + 8);
            const h8 nL1 = *(const h8*)q1p, nH1 = *(const h8*)(q1p + 8);
            const h8 nL2 = *(const h8*)q2p, nH2 = *(const h8*)(q2p + 8);
            const h8 nL3 = *(const h8*)q3p, nH3 = *(const h8*)(q3p + 8);

            STEP(cL0, cH0); STEP(cL1, cH1); STEP(cL2, cH2); STEP(cL3, cH3);

            cL0 = nL0; cH0 = nH0; cL1 = nL1; cH1 = nH1;
            cL2 = nL2; cH2 = nH2; cL3 = nL3; cH3 = nH3;
            #pragma unroll
            for (int j = 0; j < 4; ++j) fr[j] = fr[j + 4];
            fr[4] = n0; fr[5] = n1; fr[6] = n2; fr[7] = n3;
        }

        const int rem = nstep - i;   // 0..3
        if (rem > 0) STEP(cL0, cH0);
        if (rem > 1) STEP(cL1, cH1);
        if (rem > 2) STEP(cL2, cH2);

        if (isF) {
            // V = M^T E_h (bare matvec, rescaled), publish f32
            f4 d0 = MF(A[0][0], B0, Z);
            f4 d1 = MF(A[1][0], B0, Z);
            f4 d2 = MF(A[2][0], B0, Z);
            f4 d3 = MF(A[3][0], B0, Z);
            d0 = MF(A[0][1], B1, d0);
            d1 = MF(A[1][1], B1, d1);
            d2 = MF(A[2][1], B1, d2);
            d3 = MF(A[3][1], B1, d3);
            const int eb = (__builtin_amdgcn_readfirstlane(
                                __float_as_int(d0[0])) >> 23) & 0xff;
            ksum += eb - 127;
            const float sc = __int_as_float((254 - eb) << 23);
            if (cg == 0) {
                #pragma unroll
                for (int r = 0; r < 4; ++r) {
                    xbuf[16 * g + 0 * 4 + r] = d0[r] * sc;
                    xbuf[16 * g + 1 * 4 + r] = d1[r] * sc;
                    xbuf[16 * g + 2 * 4 + r] = d2[r] * sc;
                    xbuf[16 * g + 3 * 4 + r] = d3[r] * sc;
                }
            }
        } else {
            if (cg == 0) {
                #pragma unroll
                for (int sl = 0; sl < 8; ++sl) {
                    ybuf[16 * g + sl]     = (float)B0[sl];
                    ybuf[16 * g + 8 + sl] = (float)B1[sl];
                }
            }
            if (lane == 0) ks_sh = ksum;
        }
    } else {
        // ---------------- gold score, wave 2 --------------------------------
        const int* trow = tags + b * SS;
        float acc = 0.f;
        for (int s = lane; s < SS; s += 64) {
            if (mrow[s] != 0) {
                const int tag  = trow[s];
                const int prev = (s == 0) ? START_TAG : trow[s - 1];
                acc += frow[(size_t)s * TT + tag] + trans[prev * TT + tag];
            }
        }
        #pragma unroll
        for (int off = 32; off; off >>= 1) acc += __shfl_xor(acc, off);
        if (lane == 0) {
            const int end_id = trow[len - 1];
            atomicAdd(out, -(acc + trans[end_id * TT + STOP_TAG]));
        }
    }

    __syncthreads();

    if (wv == 0) {
        // Z = sum_t V[t] * u_{h+1}[t]
        float z = xbuf[lane] * ybuf[lane];
        #pragma unroll
        for (int off = 32; off; off >>= 1) z += __shfl_xor(z, off);
        if (lane == 0)
            atomicAdd(out, offs + (float)(ksum + ks_sh) * LN2
                           + LN2 * __builtin_amdgcn_logf(z));
    }
}

extern "C" void kernel_launch(void* const* d_in, const int* in_sizes, int n_in,
                              void* d_out, int out_size, void* d_ws, size_t ws_size,
                              hipStream_t stream) {
    const float* feats = (const float*)d_in[0];   // (B,S,T) f32
    const int*   mask  = (const int*)d_in[1];     // (B,S)   int (0/1)
    const int*   tags  = (const int*)d_in[2];     // (B,S)   int
    const float* trans = (const float*)d_in[3];   // (T,T)   f32
    float* out = (float*)d_out;

    (void)hipMemsetAsync(out, 0, sizeof(float), stream);
    crf_main<<<BB, 192, 0, stream>>>(feats, mask, tags, trans, out);
}